// Round 1
// baseline (216.977 us; speedup 1.0000x reference)
//
#include <hip/hip_runtime.h>
#include <math.h>

#define NUM_C 9
constexpr float W_BASE = 0.1f / 9.0f;     // 0.0111111
constexpr float W_MAIN = 0.7f;            // 1 - 0.1 - 0.2

constexpr int THREADS = 256;
constexpr int GRID = 512;                  // persistent: 2 blocks/CU x 256 CU
constexpr int CHUNK_ROWS = 1024;           // 4 rows/thread
constexpr int VECS_PER_CHUNK = CHUNK_ROWS * NUM_C / 4;   // 2304 float4
constexpr int VECS_PER_WAVE  = VECS_PER_CHUNK / 4;       // 576
constexpr int CALLS_PER_WAVE = VECS_PER_WAVE / 64;       // 9
constexpr int TVECS_PER_CHUNK = CHUNK_ROWS / 4;          // 256 int4
// LDS: 2*2304*16 + 2*256*16 = 73728 + 8192 = 81920 B = exactly 80 KB
//  -> exactly 2 blocks/CU (160 KB). Do NOT add any other __shared__!

__device__ __forceinline__ void async_copy16(const void* g, void* l) {
    __builtin_amdgcn_global_load_lds(
        (const __attribute__((address_space(1))) void*)g,
        (__attribute__((address_space(3))) void*)l,
        16 /*bytes*/, 0 /*offset*/, 0 /*aux*/);
}

// Issue exactly 10 global_load_lds (9 logits + 1 targets) for THIS wave's
// private LDS region. Wave-uniform LDS base (hardware adds lane*16).
__device__ __forceinline__ void stage_chunk(
    const float4* __restrict__ logv, const int4* __restrict__ tgtv,
    float4* lbuf, int4* tbuf, int chunk, int wave, int lane)
{
    const float4* src = logv + (long long)chunk * VECS_PER_CHUNK + wave * VECS_PER_WAVE;
    float4* dst = lbuf + wave * VECS_PER_WAVE;
#pragma unroll
    for (int i = 0; i < CALLS_PER_WAVE; i++)
        async_copy16(src + i * 64 + lane, dst + i * 64);
    async_copy16(tgtv + (long long)chunk * TVECS_PER_CHUNK + wave * 64 + lane,
                 tbuf + wave * 64);
}

// 4 rows of smoothed-label CE loss. Verbatim math from the verified kernel
// (absmax 0.0 on the harness).
__device__ __forceinline__ float rows4_loss(const float* x, const int4& t4) {
    const int tg[4] = {t4.x, t4.y, t4.z, t4.w};
    float acc = 0.0f;
#pragma unroll
    for (int k = 0; k < 4; k++) {
        const float* xr = x + k * NUM_C;
        const int t = tg[k];

        float m = xr[0];
#pragma unroll
        for (int j = 1; j < NUM_C; j++) m = fmaxf(m, xr[j]);

        float sum = 0.0f, xt = 0.0f;
#pragma unroll
        for (int j = 0; j < NUM_C; j++) {
            sum += xr[j];
            xt = (t == j) ? xr[j] : xt;
        }

        // G(t) = sum_{j>t} 2^(t-j) x[j] via backward halving scan
        float g = 0.0f, gt = 0.0f;
#pragma unroll
        for (int j = NUM_C - 1; j >= 1; j--) {
            g = 0.5f * (xr[j] + g);
            gt = (t == j - 1) ? g : gt;
        }

        float es = 0.0f;
#pragma unroll
        for (int j = 0; j < NUM_C; j++) es += __expf(xr[j] - m);
        const float lse = m + __logf(es);

        const float S = 0.98888889f - 0.2f * ldexpf(1.0f, t - 8);
        const float weighted = W_BASE * sum + (W_MAIN - W_BASE) * xt + 0.2f * gt;
        acc += lse - weighted * __builtin_amdgcn_rcpf(S);
    }
    return acc;
}

// R3 lesson (kept): NO __threadfence(); two-kernel reduction.
// New structure: persistent blocks, per-WAVE-private double-buffered LDS
// pipeline with counted s_waitcnt vmcnt(10) — the load queue never drains
// to zero in steady state (T3/T4 adapted to streaming). Each wave stages
// and reads ONLY its own LDS quarter, so the main loop needs NO barriers.
__global__ __launch_bounds__(THREADS, 2) void ccel_main(
    const float* __restrict__ logits,
    const int* __restrict__ targets,
    float* __restrict__ partials,
    int nRows)
{
    __shared__ float4 lds4[2][VECS_PER_CHUNK];   // 72 KB
    __shared__ int4   tlds[2][TVECS_PER_CHUNK];  //  8 KB

    const int tid  = threadIdx.x;
    const int wave = tid >> 6;
    const int lane = tid & 63;
    const int bid  = blockIdx.x;

    const float4* logv = (const float4*)logits;
    const int4*   tgtv = (const int4*)targets;

    const int nFull = nRows / CHUNK_ROWS;        // 3906 full chunks

    float acc = 0.0f;

    // Prologue: stage first chunk into buffer 0.
    if (bid < nFull)
        stage_chunk(logv, tgtv, &lds4[0][0], &tlds[0][0], bid, wave, lane);

    int cur = 0;
    for (int c = bid; c < nFull; c += GRID) {
        const int cn = c + GRID;
        // Previous compute's ds_reads are all retired here (zero-cost);
        // guarantees no LDS read can still be pending when the DMA that
        // overwrites this buffer (issued next iteration) lands.
        asm volatile("s_waitcnt lgkmcnt(0)" ::: "memory");
        if (cn < nFull) {
            stage_chunk(logv, tgtv, &lds4[cur ^ 1][0], &tlds[cur ^ 1][0],
                        cn, wave, lane);
            // 20 outstanding -> wait until only the newest 10 (next chunk)
            // remain in flight: current chunk is fully landed in LDS.
            asm volatile("s_waitcnt vmcnt(10)" ::: "memory");
        } else {
            asm volatile("s_waitcnt vmcnt(0)" ::: "memory");
        }
        __builtin_amdgcn_sched_barrier(0);

        // 36 consecutive floats (4 rows) via 9 ds_read_b128, own-wave region.
        float x[36];
        float4* xv = (float4*)x;
#pragma unroll
        for (int i = 0; i < 9; i++) xv[i] = lds4[cur][tid * 9 + i];
        const int4 t4 = tlds[cur][tid];

        acc += rows4_loss(x, t4);

        __builtin_amdgcn_sched_barrier(0);
        cur ^= 1;
    }

    // Partial tail chunk (< 1024 rows, multiple of 4): one block, direct
    // global loads, outside the pipeline so vmcnt accounting stays exact.
    const int tailRows = nRows - nFull * CHUNK_ROWS;
    if (tailRows > 0 && bid == (nFull % GRID)) {
        const long long rowBase = (long long)nFull * CHUNK_ROWS;
        const int myRow = tid * 4;
        if (myRow + 4 <= tailRows) {
            float x[36];
            float4* xv = (float4*)x;
            const float4* gp = logv + (rowBase * NUM_C) / 4 + tid * 9;
#pragma unroll
            for (int i = 0; i < 9; i++) xv[i] = gp[i];
            const int4 t4 = tgtv[rowBase / 4 + tid];
            acc += rows4_loss(x, t4);
        }
    }

    // Block reduce. Reuse the targets LDS for wave sums (adding even 16 B of
    // new __shared__ would push 80 KB -> >80 KB and halve occupancy).
#pragma unroll
    for (int off = 32; off > 0; off >>= 1)
        acc += __shfl_down(acc, off, 64);

    __syncthreads();                 // all DMAs landed, all compute done
    float* wsum = (float*)&tlds[0][0];
    if (lane == 0) wsum[wave] = acc;
    __syncthreads();
    if (tid == 0) {
        float bsum = 0.0f;
#pragma unroll
        for (int w = 0; w < THREADS / 64; w++) bsum += wsum[w];
        partials[bid] = bsum;
    }
}

__global__ __launch_bounds__(1024) void ccel_finish(
    const float* __restrict__ partials,
    int n,
    float* __restrict__ out,
    float invBatch)
{
    double acc = 0.0;
    for (int i = threadIdx.x; i < n; i += 1024)
        acc += (double)partials[i];

#pragma unroll
    for (int off = 32; off > 0; off >>= 1)
        acc += __shfl_down(acc, off, 64);

    __shared__ double wsum[16];
    if ((threadIdx.x & 63) == 0) wsum[threadIdx.x >> 6] = acc;
    __syncthreads();
    if (threadIdx.x == 0) {
        double total = 0.0;
#pragma unroll
        for (int w = 0; w < 16; w++) total += wsum[w];
        out[0] = (float)(total * (double)invBatch);
    }
}

extern "C" void kernel_launch(void* const* d_in, const int* in_sizes, int n_in,
                              void* d_out, int out_size, void* d_ws, size_t ws_size,
                              hipStream_t stream) {
    const float* logits = (const float*)d_in[0];
    const int* targets = (const int*)d_in[1];
    const int nRows = in_sizes[1];                 // 4,000,000

    float* partials = (float*)d_ws;

    ccel_main<<<GRID, THREADS, 0, stream>>>(logits, targets, partials, nRows);
    ccel_finish<<<1, 1024, 0, stream>>>(partials, GRID, (float*)d_out,
                                        1.0f / (float)nRows);
}

// Round 2
// 215.170 us; speedup vs baseline: 1.0084x; 1.0084x over previous
//
#include <hip/hip_runtime.h>
#include <math.h>

#define NUM_C 9
constexpr float W_BASE = 0.1f / 9.0f;     // 0.0111111
constexpr float W_MAIN = 0.7f;            // 1 - 0.1 - 0.2

constexpr int THREADS = 256;
constexpr int GRID = 1024;                 // persistent: 4 blocks/CU x 256 CU
constexpr int CHUNK_ROWS = 512;            // 2 rows/thread
constexpr int VECS_PER_CHUNK = CHUNK_ROWS * NUM_C / 4;   // 1152 float4
constexpr int TVECS_PER_CHUNK = CHUNK_ROWS / 4;          // 128 int4
// LDS: 2*1152*16 + 2*128*16 = 36864 + 4096 = 40960 B = exactly 40 KB
//  -> exactly 4 blocks/CU (160 KB), 16 waves/CU = 4 waves/SIMD.
//  Do NOT add any other __shared__ (wave sums reuse tlds).

__device__ __forceinline__ void async_copy16(const void* g, void* l) {
    __builtin_amdgcn_global_load_lds(
        (const __attribute__((address_space(1))) void*)g,
        (__attribute__((address_space(3))) void*)l,
        16 /*bytes*/, 0 /*offset*/, 0 /*aux*/);
}

// Stage one 512-row chunk (36 KB logits + 2 KB targets) with exactly 5
// global_load_lds per wave: logit calls split {5,5,4,4}, targets calls on
// waves 2,3. Cross-wave regions are fine: the consumer barrier is a full
// __syncthreads() whose vmcnt(0) covers every wave's DMAs.
__device__ __forceinline__ void stage_chunk(
    const float4* __restrict__ logv, const int4* __restrict__ tgtv,
    float4* lbuf, int4* tbuf, long long chunk, int wave, int lane)
{
    const float4* src = logv + chunk * VECS_PER_CHUNK;
    if (wave < 2) {
        const int base = wave * 320;
#pragma unroll
        for (int i = 0; i < 5; i++)
            async_copy16(src + base + i * 64 + lane, lbuf + base + i * 64);
    } else {
        const int base = 640 + (wave - 2) * 256;
#pragma unroll
        for (int i = 0; i < 4; i++)
            async_copy16(src + base + i * 64 + lane, lbuf + base + i * 64);
        const int tb = (wave - 2) * 64;
        async_copy16(tgtv + chunk * TVECS_PER_CHUNK + tb + lane, tbuf + tb);
    }
}

// 2 rows of smoothed-label CE loss. Per-row math verbatim from the verified
// kernel (absmax 0.0 on the harness).
__device__ __forceinline__ float rows2_loss(const float* x, int t0, int t1) {
    const int tg[2] = {t0, t1};
    float acc = 0.0f;
#pragma unroll
    for (int k = 0; k < 2; k++) {
        const float* xr = x + k * NUM_C;
        const int t = tg[k];

        float m = xr[0];
#pragma unroll
        for (int j = 1; j < NUM_C; j++) m = fmaxf(m, xr[j]);

        float sum = 0.0f, xt = 0.0f;
#pragma unroll
        for (int j = 0; j < NUM_C; j++) {
            sum += xr[j];
            xt = (t == j) ? xr[j] : xt;
        }

        // G(t) = sum_{j>t} 2^(t-j) x[j] via backward halving scan
        float g = 0.0f, gt = 0.0f;
#pragma unroll
        for (int j = NUM_C - 1; j >= 1; j--) {
            g = 0.5f * (xr[j] + g);
            gt = (t == j - 1) ? g : gt;
        }

        float es = 0.0f;
#pragma unroll
        for (int j = 0; j < NUM_C; j++) es += __expf(xr[j] - m);
        const float lse = m + __logf(es);

        const float S = 0.98888889f - 0.2f * ldexpf(1.0f, t - 8);
        const float weighted = W_BASE * sum + (W_MAIN - W_BASE) * xt + 0.2f * gt;
        acc += lse - weighted * __builtin_amdgcn_rcpf(S);
    }
    return acc;
}

// R3 lesson (kept): NO __threadfence(); two-kernel reduction.
// Hybrid structure: persistent double-buffered pipeline (R1) at R0's
// occupancy. Stage for chunk k+1 is issued immediately AFTER the barrier
// that publishes chunk k, so its loads fly for a full compute phase before
// the next barrier's vmcnt(0) waits on them — issue-early/wait-late without
// any hand-rolled waitcnt, race-free under cross-wave staging.
__global__ __launch_bounds__(THREADS, 4) void ccel_main(
    const float* __restrict__ logits,
    const int* __restrict__ targets,
    float* __restrict__ partials,
    int nRows)
{
    __shared__ float4 lds4[2][VECS_PER_CHUNK];   // 36 KB
    __shared__ int4   tlds[2][TVECS_PER_CHUNK];  //  4 KB

    const int tid  = threadIdx.x;
    const int wave = tid >> 6;
    const int lane = tid & 63;
    const int bid  = blockIdx.x;

    const float4* logv = (const float4*)logits;
    const int4*   tgtv = (const int4*)targets;

    const int nFull = nRows / CHUNK_ROWS;        // 7812 full chunks

    float acc = 0.0f;
    int cur = 0;

    // Prologue: stage first chunk into buffer 0.
    if (bid < nFull)
        stage_chunk(logv, tgtv, &lds4[0][0], &tlds[0][0], bid, wave, lane);

    for (int c = bid; c < nFull; c += GRID) {
        __syncthreads();   // vmcnt(0): buf[cur] landed (issued one full
                           // compute phase ago); prev compute finished.
        const int cn = c + GRID;
        if (cn < nFull)    // issue next chunk NOW; wait is next iteration
            stage_chunk(logv, tgtv, &lds4[cur ^ 1][0], &tlds[cur ^ 1][0],
                        cn, wave, lane);

        // 18 consecutive floats (2 rows) via 9 ds_read_b64.
        // Column index (9*tid+k) mod 16: stride 9, gcd(9,16)=1 -> even
        // spread, 4 lanes/column = conflict-free for b64.
        const float2* lb2 = (const float2*)&lds4[cur][0];
        const int2*   tb2 = (const int2*)&tlds[cur][0];
        float x[18];
        float2* xv = (float2*)x;
#pragma unroll
        for (int i = 0; i < 9; i++) xv[i] = lb2[tid * 9 + i];
        const int2 t2 = tb2[tid];

        acc += rows2_loss(x, t2.x, t2.y);
        cur ^= 1;
    }

    // Partial tail chunk (< 512 rows, multiple of 2): one block, direct
    // global loads, after the pipeline so vmcnt accounting stays clean.
    const int tailRows = nRows - nFull * CHUNK_ROWS;   // 256
    if (tailRows > 0 && bid == (nFull % GRID)) {
        const long long rowBase = (long long)nFull * CHUNK_ROWS;
        const int myRow = tid * 2;
        if (myRow + 2 <= tailRows) {
            float x[18];
            float2* xv = (float2*)x;
            const float2* gp = (const float2*)(logits + rowBase * NUM_C) + tid * 9;
#pragma unroll
            for (int i = 0; i < 9; i++) xv[i] = gp[i];
            const int2 t2 = ((const int2*)targets)[rowBase / 2 + tid];
            acc += rows2_loss(x, t2.x, t2.y);
        }
    }

    // Block reduce. Reuse targets LDS for wave sums (adding new __shared__
    // would push 40 KB over and drop to 3 blocks/CU).
#pragma unroll
    for (int off = 32; off > 0; off >>= 1)
        acc += __shfl_down(acc, off, 64);

    __syncthreads();                 // all DMAs landed, all compute done
    float* wsum = (float*)&tlds[0][0];
    if (lane == 0) wsum[wave] = acc;
    __syncthreads();
    if (tid == 0) {
        float bsum = 0.0f;
#pragma unroll
        for (int w = 0; w < THREADS / 64; w++) bsum += wsum[w];
        partials[bid] = bsum;
    }
}

__global__ __launch_bounds__(1024) void ccel_finish(
    const float* __restrict__ partials,
    int n,
    float* __restrict__ out,
    float invBatch)
{
    double acc = 0.0;
    for (int i = threadIdx.x; i < n; i += 1024)
        acc += (double)partials[i];

#pragma unroll
    for (int off = 32; off > 0; off >>= 1)
        acc += __shfl_down(acc, off, 64);

    __shared__ double wsum[16];
    if ((threadIdx.x & 63) == 0) wsum[threadIdx.x >> 6] = acc;
    __syncthreads();
    if (threadIdx.x == 0) {
        double total = 0.0;
#pragma unroll
        for (int w = 0; w < 16; w++) total += wsum[w];
        out[0] = (float)(total * (double)invBatch);
    }
}

extern "C" void kernel_launch(void* const* d_in, const int* in_sizes, int n_in,
                              void* d_out, int out_size, void* d_ws, size_t ws_size,
                              hipStream_t stream) {
    const float* logits = (const float*)d_in[0];
    const int* targets = (const int*)d_in[1];
    const int nRows = in_sizes[1];                 // 4,000,000

    float* partials = (float*)d_ws;

    ccel_main<<<GRID, THREADS, 0, stream>>>(logits, targets, partials, nRows);
    ccel_finish<<<1, 1024, 0, stream>>>(partials, GRID, (float*)d_out,
                                        1.0f / (float)nRows);
}